// Round 11
// baseline (1060.101 us; speedup 1.0000x reference)
//
#include <hip/hip_runtime.h>
#include <hip/hip_bf16.h>

#define NB 64      // batch
#define NT 64      // time
#define NA 64      // action dim
#define NH 1024    // hidden
#define NE 32      // embodiments
#define K2DIM 2048 // 2H

typedef unsigned short bf16_t;
typedef __attribute__((ext_vector_type(8))) short bf16x8;  // 8 bf16 = 4 VGPRs
typedef __attribute__((ext_vector_type(4))) short s16x4;   // 4 bf16 = 2 VGPRs
typedef __attribute__((ext_vector_type(4))) float f32x4;   // MFMA accumulator

__device__ __forceinline__ bf16_t f32_to_bf16(float f) {
    unsigned int u = __float_as_uint(f);
    u = (u + 0x7FFFu + ((u >> 16) & 1u)) >> 16;   // round-to-nearest-even
    return (bf16_t)u;
}
__device__ __forceinline__ unsigned cvt2(float x, float y) {
    unsigned short a = __builtin_bit_cast(unsigned short, __float2bfloat16(x));
    unsigned short b = __builtin_bit_cast(unsigned short, __float2bfloat16(y));
    return (unsigned)a | ((unsigned)b << 16);
}

// ---------------------------------------------------------------------------
// K1: a_emb = actions @ W1[cat] + b1 (K=64) and sinusoidal PE, fused.
// (verbatim r3)
// ---------------------------------------------------------------------------
__global__ __launch_bounds__(256) void k1_embed(
    const float* __restrict__ actions, const float* __restrict__ W1,
    const float* __restrict__ b1, const int* __restrict__ timesteps,
    const int* __restrict__ cat_ids, bf16_t* __restrict__ x)
{
    __shared__ float act[NT][NA];
    __shared__ float pe[64];

    const int b   = blockIdx.x;
    const int c0  = blockIdx.y * 64;
    const int tid = threadIdx.x;
    const int cat = cat_ids[b];
    const float ts = (float)timesteps[b];

    const float* ab = actions + b * (NT * NA);
    #pragma unroll
    for (int p = 0; p < 16; ++p) {
        int idx = tid + p * 256;
        act[idx >> 6][idx & 63] = ab[idx];
    }
    if (tid < 64) {
        const float kfreq = logf(10000.0f) / 512.0f;
        int c = c0 + tid;
        float v;
        if (c < 512) v = sinf(ts * expf(-(float)c * kfreq));
        else         v = cosf(ts * expf(-(float)(c - 512) * kfreq));
        pe[tid] = v;
    }
    __syncthreads();

    const int cc = tid & 63;
    const int c  = c0 + cc;
    const int t0 = tid >> 6;

    float acc[16];
    const float bias = b1[cat * NH + c];
    #pragma unroll
    for (int i = 0; i < 16; ++i) acc[i] = bias;

    const float* Wp = W1 + (size_t)cat * (NA * NH) + c;
    #pragma unroll 8
    for (int k = 0; k < NA; ++k) {
        float w = Wp[(size_t)k * NH];
        #pragma unroll
        for (int i = 0; i < 16; ++i)
            acc[i] = fmaf(act[t0 + 4 * i][k], w, acc[i]);
    }

    bf16_t* xb = x + (size_t)b * (NT * K2DIM);
    const bf16_t pv = f32_to_bf16(pe[cc]);
    #pragma unroll
    for (int i = 0; i < 16; ++i) {
        int t = t0 + 4 * i;
        xb[(size_t)t * K2DIM + c]      = f32_to_bf16(acc[i]);
        xb[(size_t)t * K2DIM + NH + c] = pv;
    }
}

// ---------------------------------------------------------------------------
// MFMA GEMM (verbatim r3 — best measured config, 157 us total).
// ---------------------------------------------------------------------------
template<int KDIM, bool SWISH, typename OutT>
__global__ __launch_bounds__(256, 2) void gemm_mfma(
    const bf16_t* __restrict__ xin, const float* __restrict__ W,
    const float* __restrict__ bias, const int* __restrict__ cat_ids,
    OutT* __restrict__ out)
{
    __shared__ __align__(128) char xs[64 * 128];   // 8 KB
    __shared__ __align__(128) char wsm[16384];     // 16 KB

    const int b    = blockIdx.x;
    const int n0   = blockIdx.y * 128;
    const int tid  = threadIdx.x;
    const int lane = tid & 63;
    const int wv   = tid >> 6;           // 0..3
    const int cat  = cat_ids[b];

    const int mw = (wv & 1) * 32;        // wave t offset
    const int nw = (wv >> 1) * 64;       // wave n offset (within 128 tile)
    const int pw = (wv >> 1) * 4;        // wave n16-tile offset
    const int l15 = lane & 15;
    const int l4  = lane >> 4;

    const bf16_t* xb = xin + (size_t)b * (size_t)NT * KDIM;
    const float*  Wb = W + (size_t)cat * KDIM * NH + n0;

    f32x4 acc[2][4];
    #pragma unroll
    for (int nf = 0; nf < 4; ++nf) {
        float bv = bias[(size_t)cat * NH + n0 + nw + nf * 16 + l15];
        acc[0][nf] = (f32x4){bv, bv, bv, bv};
        acc[1][nf] = acc[0][nf];
    }

    const unsigned wbase = (unsigned)(unsigned long long)&wsm[0];
    const unsigned laneB = wbase + (unsigned)(l4 * 2048 + l15 * 8);

    for (int kc = 0; kc < KDIM / 64; ++kc) {
        const bf16_t* xsrc = xb + kc * 64;
        const float*  Wp   = Wb + (size_t)(kc * 64) * NH;

        __syncthreads();   // prior-iter LDS reads done before overwrite

        #pragma unroll
        for (int p = 0; p < 2; ++p) {
            int id = tid + p * 256;
            int t  = id >> 3;
            int k8 = id & 7;
            uint4 v = *(const uint4*)(xsrc + (size_t)t * KDIM + k8 * 8);
            int off = (t * 128 + k8 * 16) ^ ((t & 7) << 4);
            *(uint4*)(xs + off) = v;
        }
        #pragma unroll
        for (int p = 0; p < 4; ++p) {
            int id  = tid + p * 256;      // 0..1023
            int k   = id >> 4;            // 0..63
            int oct = id & 15;            // 0..15 (n = oct*8)
            const float* src = Wp + (size_t)k * NH + oct * 8;
            float4 w0 = *(const float4*)(src);
            float4 w1 = *(const float4*)(src + 4);
            uint4 pk;
            pk.x = cvt2(w0.x, w0.y);
            pk.y = cvt2(w0.z, w0.w);
            pk.z = cvt2(w1.x, w1.y);
            pk.w = cvt2(w1.z, w1.w);
            int off = ((k >> 2) * 8 + (oct >> 1)) * 128 + (k & 3) * 32 + (oct & 1) * 16;
            *(uint4*)(wsm + off) = pk;
        }
        __syncthreads();

        #pragma unroll
        for (int ks = 0; ks < 2; ++ks) {
            bf16x8 af[2];
            #pragma unroll
            for (int m = 0; m < 2; ++m) {
                int row = mw + m * 16 + l15;
                int off = (row * 128 + ks * 64 + l4 * 16) ^ ((row & 7) << 4);
                af[m] = *(const bf16x8*)(xs + off);
            }
            bf16x8 bfr[4];
            #pragma unroll
            for (int nf = 0; nf < 4; ++nf) {
                unsigned a = laneB + (unsigned)(ks * 8192 + (pw + nf) * 128);
                s16x4 lo, hi;
                asm volatile("ds_read_b64_tr_b16 %0, %1" : "=v"(lo) : "v"(a));
                asm volatile("ds_read_b64_tr_b16 %0, %1 offset:1024" : "=v"(hi) : "v"(a));
                bfr[nf] = __builtin_shufflevector(lo, hi, 0, 1, 2, 3, 4, 5, 6, 7);
            }
            asm volatile("s_waitcnt lgkmcnt(0)" ::: "memory");
            __builtin_amdgcn_sched_barrier(0);
            #pragma unroll
            for (int m = 0; m < 2; ++m)
                #pragma unroll
                for (int nf = 0; nf < 4; ++nf)
                    acc[m][nf] = __builtin_amdgcn_mfma_f32_16x16x32_bf16(
                        af[m], bfr[nf], acc[m][nf], 0, 0, 0);
        }
    }

    #pragma unroll
    for (int m = 0; m < 2; ++m) {
        #pragma unroll
        for (int nf = 0; nf < 4; ++nf) {
            int col = n0 + nw + nf * 16 + l15;
            #pragma unroll
            for (int r = 0; r < 4; ++r) {
                int row = mw + m * 16 + l4 * 4 + r;
                float h = acc[m][nf][r];
                if (SWISH) h = h / (1.0f + __expf(-h));
                if constexpr (sizeof(OutT) == 2) {
                    out[((size_t)b * NT + row) * NH + col] = (OutT)f32_to_bf16(h);
                } else {
                    out[((size_t)b * NT + row) * NH + col] = h;
                }
            }
        }
    }
}

// ---------------------------------------------------------------------------
// PROBE A: free-running W stream with r3's DUPLICATED per-batch demand.
// grid (64, 8) like r3-K2; no LDS, no barriers; float4 coalesced, unroll-8.
// Measures achievable ingest for this access pattern/grid.
// ---------------------------------------------------------------------------
template<int REPS>
__global__ __launch_bounds__(256) void probe_wdup(
    const float* __restrict__ W, const int* __restrict__ cat_ids,
    float* __restrict__ sink)
{
    const int b   = blockIdx.x;
    const int n0  = blockIdx.y * 128;
    const int cat = cat_ids[b];
    const int tid = threadIdx.x;
    const float* Wp = W + (size_t)cat * K2DIM * NH + n0 + (tid & 31) * 4;
    float4 acc = {0.f, 0.f, 0.f, 0.f};
    for (int r = 0; r < REPS; ++r) {
        #pragma unroll 8
        for (int k = tid >> 5; k < K2DIM; k += 8) {
            float4 v = *(const float4*)(Wp + (size_t)k * NH);
            acc.x += v.x; acc.y += v.y; acc.z += v.z; acc.w += v.w;
        }
    }
    sink[(blockIdx.y * NB + b) * 256 + tid] = acc.x + acc.y + acc.z + acc.w;
}

// ---------------------------------------------------------------------------
// PROBE B: unique-W stream. 256 blocks (32 cats x 8 n-tiles), 1024 thr
// (1 block/CU, 16 waves). Best-case W ingest calibration.
// ---------------------------------------------------------------------------
template<int REPS>
__global__ __launch_bounds__(1024) void probe_wuniq(
    const float* __restrict__ W, float* __restrict__ sink)
{
    const int cat = blockIdx.x & 31;
    const int n0  = (blockIdx.x >> 5) * 128;
    const int tid = threadIdx.x;   // 0..1023
    const float* Wp = W + (size_t)cat * K2DIM * NH + n0 + (tid & 31) * 4;
    float4 acc = {0.f, 0.f, 0.f, 0.f};
    for (int r = 0; r < REPS; ++r) {
        #pragma unroll 8
        for (int k = tid >> 5; k < K2DIM; k += 32) {
            float4 v = *(const float4*)(Wp + (size_t)k * NH);
            acc.x += v.x; acc.y += v.y; acc.z += v.z; acc.w += v.w;
        }
    }
    sink[blockIdx.x * 1024 + tid] = acc.x + acc.y + acc.z + acc.w;
}

// ---------------------------------------------------------------------------
// PROBE C: r3-K2 staging loop ONLY (x + W staging, both barriers, LDS writes)
// with tr-reads/MFMA/epilogue stripped; tiny LDS consume keeps stores live.
// ---------------------------------------------------------------------------
template<int REPS>
__global__ __launch_bounds__(256, 2) void probe_stage(
    const bf16_t* __restrict__ xin, const float* __restrict__ W,
    const int* __restrict__ cat_ids, float* __restrict__ sink)
{
    __shared__ __align__(128) char xs[64 * 128];
    __shared__ __align__(128) char wsm[16384];

    const int b    = blockIdx.x;
    const int n0   = blockIdx.y * 128;
    const int tid  = threadIdx.x;
    const int cat  = cat_ids[b];

    const bf16_t* xb = xin + (size_t)b * (size_t)NT * K2DIM;
    const float*  Wb = W + (size_t)cat * K2DIM * NH + n0;

    float acc = 0.0f;
    for (int rep = 0; rep < REPS; ++rep) {
        for (int kc = 0; kc < K2DIM / 64; ++kc) {
            const bf16_t* xsrc = xb + kc * 64;
            const float*  Wp   = Wb + (size_t)(kc * 64) * NH;
            __syncthreads();
            #pragma unroll
            for (int p = 0; p < 2; ++p) {
                int id = tid + p * 256;
                int t  = id >> 3;
                int k8 = id & 7;
                uint4 v = *(const uint4*)(xsrc + (size_t)t * K2DIM + k8 * 8);
                int off = (t * 128 + k8 * 16) ^ ((t & 7) << 4);
                *(uint4*)(xs + off) = v;
            }
            #pragma unroll
            for (int p = 0; p < 4; ++p) {
                int id  = tid + p * 256;
                int k   = id >> 4;
                int oct = id & 15;
                const float* src = Wp + (size_t)k * NH + oct * 8;
                float4 w0 = *(const float4*)(src);
                float4 w1 = *(const float4*)(src + 4);
                uint4 pk;
                pk.x = cvt2(w0.x, w0.y);
                pk.y = cvt2(w0.z, w0.w);
                pk.z = cvt2(w1.x, w1.y);
                pk.w = cvt2(w1.z, w1.w);
                int off = ((k >> 2) * 8 + (oct >> 1)) * 128 + (k & 3) * 32 + (oct & 1) * 16;
                *(uint4*)(wsm + off) = pk;
            }
            __syncthreads();
            // stand-in consume (keeps LDS traffic live; negligible cost)
            acc += *(const float*)(xs + ((tid * 16) & 8191))
                 + *(const float*)(wsm + ((tid * 16) & 16383));
        }
    }
    sink[(blockIdx.y * NB + b) * 256 + tid] = acc;
}

extern "C" void kernel_launch(void* const* d_in, const int* in_sizes, int n_in,
                              void* d_out, int out_size, void* d_ws, size_t ws_size,
                              hipStream_t stream) {
    const float* actions   = (const float*)d_in[0];
    const float* W1        = (const float*)d_in[1];
    const float* b1        = (const float*)d_in[2];
    const float* W2        = (const float*)d_in[3];
    const float* b2        = (const float*)d_in[4];
    const float* W3        = (const float*)d_in[5];
    const float* b3        = (const float*)d_in[6];
    const int*   timesteps = (const int*)d_in[7];
    const int*   cat_ids   = (const int*)d_in[8];
    float* out = (float*)d_out;

    // ws: x bf16 [B][T][2H] (16.8 MB) then y bf16 [B][T][H] (8.4 MB)
    bf16_t* x = (bf16_t*)d_ws;
    bf16_t* y = x + (size_t)NB * NT * K2DIM;

    // probe sinks live INSIDE the x region: k1 fully rewrites x at the start
    // of every call, and probes run after K3 has consumed y -> deterministic.
    float* sinkA = (float*)x;                    // 512 KB
    float* sinkB = sinkA + 512 * 256;            // 1 MB
    float* sinkC = sinkB + 256 * 1024;           // 512 KB

    // --- real pipeline (r3 exact) ---
    k1_embed<<<dim3(NB, NH / 64), 256, 0, stream>>>(actions, W1, b1, timesteps, cat_ids, x);
    gemm_mfma<K2DIM, true,  bf16_t><<<dim3(NB, NH / 128), 256, 0, stream>>>(x, W2, b2, cat_ids, y);
    gemm_mfma<NH,    false, float ><<<dim3(NB, NH / 128), 256, 0, stream>>>(y, W3, b3, cat_ids, out);

    // --- measurement probes (deterministic, ws-only writes) ---
    probe_wdup<4><<<dim3(NB, 8), 256, 0, stream>>>(W2, cat_ids, sinkA);
    probe_wuniq<8><<<dim3(256), 1024, 0, stream>>>(W2, sinkB);
    probe_stage<4><<<dim3(NB, 8), 256, 0, stream>>>(x, W2, cat_ids, sinkC);
}